// Round 2
// baseline (70.807 us; speedup 1.0000x reference)
//
#include <hip/hip_runtime.h>
#include <math.h>

// CapsuleLayer routing via MFMA (u_hat never materialized):
//   logit[n,m] = in[n,:] @ cumwv[:,m]     (K=16 bf16 MFMA, C: row=n,col=m)
//   e = exp2(logit)   (cumwv prescaled by log2 e)
//   xc[m,d] = sum_n e[n,m] in[n,d]; S[m] = sum_n e[n,m]   (E^T @ in, MFMA)
//   s = (xc/S) @ W_m (fp32 tail); v = squash(s); cumwv += W_m @ v
//
// R18: latency-chain surgery (R17 showed instr-count cuts barely move it):
//  - logit MFMA -> 16x16x16_bf16 (K=16 exact, no zero half; 2-VGPR frags),
//    __has_builtin-guarded with x32 zero-pad fallback.
//  - ALL pass-invariant frags hoisted to registers before the pass loop:
//    a0/a1 (4t x 2 VGPR each, loaded DIRECT from global, L2-hot) and
//    bi (4t x 4 VGPR from inT). innorm LDS array deleted.
//  - e-regroup LDS round-trip -> 4 dword shfls (ds_bpermute, no
//    store-to-load hazard). Exchange table re-derived from the R15-verified
//    psi layout: q0<-[w0^0,w0^1] q1<-[w0^2,w0^3] q2<-[w1^0,w1^1]
//    q3<-[w1^2,w1^3]; sender/receiver consistency checked per shfl.
//  - tail broadcast chains (16-step shfl dots) -> tbx LDS round-trip +
//    4x b128 broadcast reads; staging colsum fully reduced (pass-0 tail
//    16 reads, was 64).

#define TPB 1024
#define LOG2E 1.44269504088896f

typedef __attribute__((ext_vector_type(8))) short short8;   // 8 bf16 = 4 VGPR
typedef __attribute__((ext_vector_type(4))) short short4v;  // 4 bf16 = 2 VGPR
typedef __attribute__((ext_vector_type(4))) float float4v;  // MFMA acc

#if defined(__has_builtin)
#if __has_builtin(__builtin_amdgcn_mfma_f32_16x16x16bf16_1k)
#define HAVE_MFMA16 1
#endif
#endif

#define DPP_ADDF(x, ctrl) \
    ((x) + __int_as_float(__builtin_amdgcn_update_dpp( \
        0, __float_as_int(x), (ctrl), 0xF, 0xF, true)))
// row_shl:4 = 0x104, row_shl:8 = 0x108

static __device__ inline unsigned short f2bf(float x) {     // RNE f32->bf16
    unsigned u = __float_as_uint(x);
    return (unsigned short)((u + 0x7FFFu + ((u >> 16) & 1u)) >> 16);
}
static __device__ inline unsigned pk2(float a, float b) {
    return (unsigned)f2bf(a) | ((unsigned)f2bf(b) << 16);
}

__global__ __launch_bounds__(TPB, 2)
void capsule_routing_kernel(const float* __restrict__ in,
                            const float* __restrict__ W,
                            float* __restrict__ out)
{
    __shared__ unsigned short inT[16 * 2056];      // bf16 in^T[d][n]+pad  64.3 KB
    __shared__ float scratch[16][320];             // per-wave multiplex   20 KB:
        // staging: colsum (fully reduced) [d]  (16 floats)
        // reduce:  xc [m*17 + d], S at [272+ml]
    __shared__ unsigned short cumT[16 * 24];       // bf16 cumwv*LOG2E [m][d]
    __shared__ float tbx[4][64];                   // tail broadcast [wt][m&3][d]

    const int tid  = threadIdx.x;
    const int w    = tid >> 6;       // 0..15
    const int l    = tid & 63;
    const int ml   = l & 15;         // MFMA row/col owner index
    const int quad = l >> 4;         // 0..3
    const int b    = blockIdx.x & 63;
    const int m0g  = (blockIdx.x >> 6) << 4;   // 0 or 16

    const float4* gin4 = (const float4*)(in + ((size_t)b << 15));

    // ---- stage: fp32 dense float4 reads -> bf16 inT (transposed) only;
    //      colsum fully reduced on the fly. Thread owns 8 consecutive rows,
    //      even row-rotation de-aligns the bank stride.
    {
        const int d0   = (tid & 3) * 4;
        const int g    = tid >> 2;          // 0..255 row-group
        const int n0   = g << 3;            // 8 rows per group
        const int rot2 = (g & 3) << 1;      // even rotation -> pairs intact
        float c0 = 0.f, c1 = 0.f, c2 = 0.f, c3 = 0.f;
        unsigned pk32[4][4];                // [col i][row-pair j], static idx
        #pragma unroll
        for (int k = 0; k < 8; ++k) {
            const int n = n0 + ((k + rot2) & 7);
            const float4 gv = gin4[n * 4 + (tid & 3)];
            c0 += gv.x; c1 += gv.y; c2 += gv.z; c3 += gv.w;
            const unsigned short u0 = f2bf(gv.x), u1 = f2bf(gv.y),
                                 u2 = f2bf(gv.z), u3 = f2bf(gv.w);
            const int j = k >> 1;
            if ((k & 1) == 0) {
                pk32[0][j] = u0; pk32[1][j] = u1;
                pk32[2][j] = u2; pk32[3][j] = u3;
            } else {
                pk32[0][j] |= (unsigned)u0 << 16; pk32[1][j] |= (unsigned)u1 << 16;
                pk32[2][j] |= (unsigned)u2 << 16; pk32[3][j] |= (unsigned)u3 << 16;
            }
        }
        #pragma unroll
        for (int j = 0; j < 4; ++j) {       // 16 x b32 inT writes (row pairs)
            const int nn = n0 + ((2 * j + rot2) & 7);     // even -> 4B aligned
            *(unsigned*)&inT[(d0 + 0) * 2056 + nn] = pk32[0][j];
            *(unsigned*)&inT[(d0 + 1) * 2056 + nn] = pk32[1][j];
            *(unsigned*)&inT[(d0 + 2) * 2056 + nn] = pk32[2][j];
            *(unsigned*)&inT[(d0 + 3) * 2056 + nn] = pk32[3][j];
        }
        // full colsum reduce: DPP within 16-lane row, shfl across quads
        c0 = DPP_ADDF(c0, 0x104); c0 = DPP_ADDF(c0, 0x108);
        c1 = DPP_ADDF(c1, 0x104); c1 = DPP_ADDF(c1, 0x108);
        c2 = DPP_ADDF(c2, 0x104); c2 = DPP_ADDF(c2, 0x108);
        c3 = DPP_ADDF(c3, 0x104); c3 = DPP_ADDF(c3, 0x108);
        c0 += __shfl_xor(c0, 16); c0 += __shfl_xor(c0, 32);
        c1 += __shfl_xor(c1, 16); c1 += __shfl_xor(c1, 32);
        c2 += __shfl_xor(c2, 16); c2 += __shfl_xor(c2, 32);
        c3 += __shfl_xor(c3, 16); c3 += __shfl_xor(c3, 32);
        if (l < 4) {
            float4 v4; v4.x = c0; v4.y = c1; v4.z = c2; v4.w = c3;
            *(float4*)&scratch[w][l * 4] = v4;   // scratch[w][d] = wave colsum
        }
    }

    // ---- prologue: hoist ALL pass-invariant fragments into registers.
    //      A-frags direct from global (L2-hot, perfectly coalesced 16B/lane);
    //      bi from inT (own wave's rows -> no barrier needed).
#ifdef HAVE_MFMA16
    short4v a0h[4], a1h[4];          // A[n=ml][k=d=quad*4+j]
#else
    short8 a0h[4], a1h[4];           // zero-padded K=32 fallback
#endif
    short8 bih[4];                   // B[k=n_local][d=ml]
    #pragma unroll
    for (int t = 0; t < 4; ++t) {
        const int nb = (w << 7) + (t << 5);
#ifdef HAVE_MFMA16
        {
            const float4 ga = gin4[(nb + ml) * 4 + quad];
            const float4 gb = gin4[(nb + 16 + ml) * 4 + quad];
            short4v a; a[0] = (short)f2bf(ga.x); a[1] = (short)f2bf(ga.y);
                       a[2] = (short)f2bf(ga.z); a[3] = (short)f2bf(ga.w);
            short4v c; c[0] = (short)f2bf(gb.x); c[1] = (short)f2bf(gb.y);
                       c[2] = (short)f2bf(gb.z); c[3] = (short)f2bf(gb.w);
            a0h[t] = a; a1h[t] = c;
        }
#else
        {
            short8 a = {0,0,0,0,0,0,0,0}, c = {0,0,0,0,0,0,0,0};
            if (quad < 2) {
                const float4 g0 = gin4[(nb + ml) * 4 + quad * 2];
                const float4 g1 = gin4[(nb + ml) * 4 + quad * 2 + 1];
                const float4 h0 = gin4[(nb + 16 + ml) * 4 + quad * 2];
                const float4 h1 = gin4[(nb + 16 + ml) * 4 + quad * 2 + 1];
                a[0]=(short)f2bf(g0.x); a[1]=(short)f2bf(g0.y);
                a[2]=(short)f2bf(g0.z); a[3]=(short)f2bf(g0.w);
                a[4]=(short)f2bf(g1.x); a[5]=(short)f2bf(g1.y);
                a[6]=(short)f2bf(g1.z); a[7]=(short)f2bf(g1.w);
                c[0]=(short)f2bf(h0.x); c[1]=(short)f2bf(h0.y);
                c[2]=(short)f2bf(h0.z); c[3]=(short)f2bf(h0.w);
                c[4]=(short)f2bf(h1.x); c[5]=(short)f2bf(h1.y);
                c[6]=(short)f2bf(h1.z); c[7]=(short)f2bf(h1.w);
            }
            a0h[t] = a; a1h[t] = c;
        }
#endif
        bih[t] = *(const short8*)&inT[ml * 2056 + nb + quad * 8];
    }

    // e-exchange constants (verified against R15 psi-layout read pattern):
    //   receiver frag = q0:[w0^0,w0^1] q1:[w0^2,w0^3] q2:[w1^0,w1^1] q3:[w1^2,w1^3]
    const int srcAB = ml + ((quad == 0) ? 16 : (quad == 1) ? 32 : 0);
    const int srcCD = ml + ((quad == 1) ? 48 : (quad == 3) ? 32 : 16);
    const bool selAB = (quad == 1) || (quad == 2);
    const bool selC  = (quad == 3);

    float cwv = 0.f;   // tail threads: cumulative wv[m][d=tc], fp32

    for (int pass = 0; pass < 3; ++pass) {
        // ---------- sweep (passes 1,2): MFMA chunks of 32 n ----------
        if (pass) {
#ifdef HAVE_MFMA16
            const short4v bc = *(const short4v*)&cumT[ml * 24 + quad * 4];
#else
            short8 bc = {0,0,0,0,0,0,0,0};
            if (quad < 2)
                bc = *(const short8*)&cumT[ml * 24 + quad * 8];
#endif
            float4v xc = {0.f, 0.f, 0.f, 0.f};
            float Sp = 0.f;

            #pragma unroll
            for (int t = 0; t < 4; ++t) {
                const float4v z = {0.f, 0.f, 0.f, 0.f};
#ifdef HAVE_MFMA16
                float4v c0 = __builtin_amdgcn_mfma_f32_16x16x16bf16_1k(a0h[t], bc, z, 0, 0, 0);
                float4v c1 = __builtin_amdgcn_mfma_f32_16x16x16bf16_1k(a1h[t], bc, z, 0, 0, 0);
#else
                float4v c0 = __builtin_amdgcn_mfma_f32_16x16x32_bf16(a0h[t], bc, z, 0, 0, 0);
                float4v c1 = __builtin_amdgcn_mfma_f32_16x16x32_bf16(a1h[t], bc, z, 0, 0, 0);
#endif
                // e = exp2(logit); C: row n = quad*4+r, col m = ml
                float e00 = exp2f(c0[0]), e01 = exp2f(c0[1]),
                      e02 = exp2f(c0[2]), e03 = exp2f(c0[3]);
                float e10 = exp2f(c1[0]), e11 = exp2f(c1[1]),
                      e12 = exp2f(c1[2]), e13 = exp2f(c1[3]);
                Sp += (e00 + e01) + (e02 + e03) + (e10 + e11) + (e12 + e13);
                const unsigned d00 = pk2(e00, e01), d01 = pk2(e02, e03);
                const unsigned d10 = pk2(e10, e11), d11 = pk2(e12, e13);
                // 4-shfl e-regroup (no LDS round-trip):
                const unsigned RA = (unsigned)__shfl((int)(selAB ? d00 : d10), srcAB);
                const unsigned RB = (unsigned)__shfl((int)(selAB ? d01 : d11), srcAB);
                const unsigned RC = (unsigned)__shfl((int)(selC  ? d00 : d10), srcCD);
                const unsigned RD = (unsigned)__shfl((int)(selC  ? d01 : d11), srcCD);
                union { unsigned u[4]; short8 s; } ua;
                ua.u[0] = (quad == 0) ? d00 : (selC ? RC : RA);
                ua.u[1] = (quad == 0) ? d01 : (selC ? RD : RB);
                ua.u[2] = (quad == 0) ? RA  : (selC ? d10 : RC);
                ua.u[3] = (quad == 0) ? RB  : (selC ? d11 : RD);
                xc = __builtin_amdgcn_mfma_f32_16x16x32_bf16(ua.s, bih[t], xc, 0, 0, 0);
            }
            // S: reduce over quads (same m = ml)
            Sp += __shfl_xor(Sp, 16);
            Sp += __shfl_xor(Sp, 32);
            #pragma unroll
            for (int r = 0; r < 4; ++r)
                scratch[w][(quad * 4 + r) * 17 + ml] = xc[r];
            if (l < 16) scratch[w][272 + l] = Sp;
        }
        __syncthreads();   // scratch slots ready (pass 0: staging colsum)

        // ---------- tail: 4 waves, thread = (m = tid>>4, tc = tid&15) ------
        if (tid < 256) {
            const int m  = tid >> 4;
            const int tc = tid & 15;
            const int wt = tid >> 6;
            const int mr = m & 3;
            float Stot, xtot = 0.f;
            if (pass == 0) {
                Stot = 2048.f;
                #pragma unroll
                for (int w2 = 0; w2 < 16; ++w2)
                    xtot += scratch[w2][tc];
            } else {
                Stot = 0.f;
                #pragma unroll
                for (int w2 = 0; w2 < 16; ++w2) {
                    Stot += scratch[w2][272 + m];
                    xtot += scratch[w2][m * 17 + tc];
                }
            }
            // broadcast xtot(m, all d) to the 16-lane group via tbx
            tbx[wt][mr * 16 + tc] = xtot;
            const float4 x0 = *(const float4*)&tbx[wt][mr * 16 + 0];
            const float4 x1 = *(const float4*)&tbx[wt][mr * 16 + 4];
            const float4 x2 = *(const float4*)&tbx[wt][mr * 16 + 8];
            const float4 x3 = *(const float4*)&tbx[wt][mr * 16 + 12];
            // s(m,tc) = (1/S) sum_d xtot(m,d) * W[d][m0g+m][tc]  (W L2-hot)
            const float* Wb = &W[((m0g + m) << 4) + tc];
            float s = x0.x * Wb[0 << 9]  + x0.y * Wb[1 << 9]
                    + x0.z * Wb[2 << 9]  + x0.w * Wb[3 << 9]
                    + x1.x * Wb[4 << 9]  + x1.y * Wb[5 << 9]
                    + x1.z * Wb[6 << 9]  + x1.w * Wb[7 << 9]
                    + x2.x * Wb[8 << 9]  + x2.y * Wb[9 << 9]
                    + x2.z * Wb[10 << 9] + x2.w * Wb[11 << 9]
                    + x3.x * Wb[12 << 9] + x3.y * Wb[13 << 9]
                    + x3.z * Wb[14 << 9] + x3.w * Wb[15 << 9];
            s /= Stot;
            float n2 = s * s;
            n2 += __shfl_xor(n2, 1);
            n2 += __shfl_xor(n2, 2);
            n2 += __shfl_xor(n2, 4);
            n2 += __shfl_xor(n2, 8);
            const float nr = sqrtf(n2);
            const float v  = s * (n2 / (1.f + n2)) / (nr + 1e-7f);
            if (pass < 2) {
                // wv(m, d=tc) = sum_c W[tc][m][c] * v[c]; broadcast v via tbx
                tbx[wt][mr * 16 + tc] = v;
                const float4 v0 = *(const float4*)&tbx[wt][mr * 16 + 0];
                const float4 v1 = *(const float4*)&tbx[wt][mr * 16 + 4];
                const float4 v2 = *(const float4*)&tbx[wt][mr * 16 + 8];
                const float4 v3 = *(const float4*)&tbx[wt][mr * 16 + 12];
                const float4* Wrow = (const float4*)&W[(tc << 9) + ((m0g + m) << 4)];
                const float4 w0 = Wrow[0], w1 = Wrow[1], w2 = Wrow[2], w3 = Wrow[3];
                float wvv = w0.x * v0.x + w0.y * v0.y + w0.z * v0.z + w0.w * v0.w
                          + w1.x * v1.x + w1.y * v1.y + w1.z * v1.z + w1.w * v1.w
                          + w2.x * v2.x + w2.y * v2.y + w2.z * v2.z + w2.w * v2.w
                          + w3.x * v3.x + w3.y * v3.y + w3.z * v3.z + w3.w * v3.w;
                cwv += wvv;
                cumT[m * 24 + tc] = f2bf(cwv * LOG2E);   // m-major
            } else {
                out[((size_t)b << 9) + ((m0g + m) << 4) + tc] = v;
            }
        }
        if (pass < 2) __syncthreads();   // cum ready for next sweep
    }
}

extern "C" void kernel_launch(void* const* d_in, const int* in_sizes, int n_in,
                              void* d_out, int out_size, void* d_ws, size_t ws_size,
                              hipStream_t stream) {
    (void)in_sizes; (void)n_in; (void)d_ws; (void)ws_size; (void)out_size;
    const float* in = (const float*)d_in[0];
    const float* W  = (const float*)d_in[1];
    float* out = (float*)d_out;
    hipLaunchKernelGGL(capsule_routing_kernel, dim3(128), dim3(TPB), 0, stream,
                       in, W, out);
}